// Round 11
// baseline (467.990 us; speedup 1.0000x reference)
//
#include <hip/hip_runtime.h>
#include <stdint.h>

// SubResidualGeoLossl on MI355X — fp16 single-term MFMA, r6 schedule @ w=5.
//   h   = relu( sum_k gather(concat(x,y), nbr[k]) @ w1[k] + b1 )   K=128
//   out = clip( sum_k gather(h,           nbr[k]) @ w2[k] + b2 , -2, 2)  K=64
// Ledger: r7 burst-prefetch +traffic; r8 w=8 spill; r9 w=6 spill (unified
// VGPR+AGPR need ~84 > 85-budget-with-temps); r10 mi=1 TLP test: occupancy
// 60% but SLOWER -> gather path pinned at ~10 TB/s across all configs.
// This round: r6 verbatim + launch_bounds(256,5) (budget 102 >= 84, no spill).

#define NPTS 400000
#define TAPS 27

typedef __attribute__((ext_vector_type(8))) _Float16 f16x8;
typedef __attribute__((ext_vector_type(4))) float f32x4;

#define MFMA16(a, b, c) __builtin_amdgcn_mfma_f32_16x16x32_f16(a, b, c, 0, 0, 0)

// ---- scratch layout (bytes) ----
// h16:  [NPTS+1][64] fp16 (128 B/row, row NPTS zero)              51.2 MB
// w1t:  [27][64 col][128 k] fp16, pre-swizzled q^=((q>>8)&15)<<4   432 KB
// w2t:  [27][64 col][64 k]  fp16, pre-swizzled q^=((q>>7)&7)<<4    216 KB
// xy16: [NPTS+1][128] fp16 (256 B/row, row NPTS zero)            102.4 MB
#define H16_BYTES ((size_t)(NPTS + 1) * 128)
#define W1T_SZ    ((size_t)TAPS * 64 * 128 * 2)
#define W2T_SZ    ((size_t)TAPS * 64 * 64 * 2)
#define W1T_OFF   (H16_BYTES)
#define W2T_OFF   (W1T_OFF + W1T_SZ)
#define XY16_OFF  (W2T_OFF + W2T_SZ)

__device__ inline void gload_lds16(const void* g, void* l) {
    __builtin_amdgcn_global_load_lds((const __attribute__((address_space(1))) void*)g,
                                     (__attribute__((address_space(3))) void*)l, 16, 0, 0);
}

// ---- prep: transpose + fp16-quantize + PRE-SWIZZLE weights; zero h16 sentinel ----
__global__ __launch_bounds__(256) void prep_weights(
    const float* __restrict__ w1, const float* __restrict__ w2,
    _Float16* __restrict__ w1t, _Float16* __restrict__ w2t,
    _Float16* __restrict__ h16)
{
    const int gid = blockIdx.x * 256 + threadIdx.x;
    const int n1 = TAPS * 64 * 128;   // 221184
    const int n2 = TAPS * 64 * 64;    // 110592
    if (gid < n1) {
        const int tap = gid >> 13;
        const int q  = (gid & 8191) << 1;            // byte within 16KB tap block
        const int sb = q ^ (((q >> 8) & 15) << 4);   // inverse swizzle (involution)
        const int col = sb >> 8, k = (sb & 255) >> 1;
        w1t[gid] = (_Float16)w1[((size_t)tap * 128 + k) * 64 + col];
    } else if (gid < n1 + n2) {
        const int g = gid - n1;
        const int tap = g >> 12;
        const int q  = (g & 4095) << 1;              // byte within 8KB tap block
        const int sb = q ^ (((q >> 7) & 7) << 4);
        const int col = sb >> 7, k = (sb & 127) >> 1;
        w2t[g] = (_Float16)w2[((size_t)tap * 64 + k) * 64 + col];
    } else if (gid < n1 + n2 + 64) {
        h16[(size_t)NPTS * 64 + (gid - n1 - n2)] = (_Float16)0.f;  // sentinel row
    }
}

// ---- prep: concat(x,y) -> fp16 rows [NPTS+1][128] (sentinel row zero) ----
__global__ __launch_bounds__(256) void prep_xy16(
    const float* __restrict__ x, const float* __restrict__ y,
    _Float16* __restrict__ xy16)
{
    const int gid = blockIdx.x * 256 + threadIdx.x;
    if (gid >= (NPTS + 1) * 16) return;
    const int p = gid >> 4, seg = gid & 15;   // seg: 8-channel group of concat(x,y)
    f32x4 v0 = {0.f, 0.f, 0.f, 0.f}, v1 = {0.f, 0.f, 0.f, 0.f};
    if (p < NPTS) {
        const float* s = (seg < 8) ? (x + (size_t)p * 64 + seg * 8)
                                   : (y + (size_t)p * 64 + (seg - 8) * 8);
        v0 = *(const f32x4*)s; v1 = *(const f32x4*)(s + 4);
    }
    _Float16 h[8];
#pragma unroll
    for (int j = 0; j < 4; ++j) { h[j] = (_Float16)v0[j]; h[4 + j] = (_Float16)v1[j]; }
    *(f16x8*)&xy16[(size_t)p * 128 + seg * 8] = *(f16x8*)h;
}

// =====================================================================
// conv1: K=128, A gathered fp16 from xy16 (256 B/row), mi=2
// Schedule = r6 VERBATIM; only change: waves/EU 4 -> 5 (budget 102, no spill).
// =====================================================================
__global__ __launch_bounds__(256, 5) void conv1_kernel(
    const _Float16* __restrict__ xy16,
    const _Float16* __restrict__ w1t,
    const float* __restrict__ b1, const int* __restrict__ nbr,
    _Float16* __restrict__ h16)
{
    __shared__ char wsh[16384];   // W[64 col][128 k] fp16, XOR(c<<4)-swizzled

    const int tid = threadIdx.x;
    const int wv = tid >> 6, ln = tid & 63;
    const int g4 = ln >> 4, c = ln & 15;
    const int base = blockIdx.x * 128 + wv * 32;

    f32x4 acc[2][4];
    {
        float bv[4];
#pragma unroll
        for (int nf = 0; nf < 4; ++nf) bv[nf] = b1[16 * nf + c];
#pragma unroll
        for (int mi = 0; mi < 2; ++mi)
#pragma unroll
            for (int nf = 0; nf < 4; ++nf)
                acc[mi][nf] = (f32x4){bv[nf], bv[nf], bv[nf], bv[nf]};
    }

    int gi[2], gin[2];
    f16x8 aA[2], aB[2];

#define LOAD_IDX1(dst, tp) do { \
    _Pragma("unroll") for (int mi = 0; mi < 2; ++mi) \
        dst[mi] = nbr[(size_t)(tp) * NPTS + base + mi * 16 + c]; \
    } while (0)

#define GPRE1(dst, kf) do { \
    _Pragma("unroll") for (int mi = 0; mi < 2; ++mi) { \
        const char* row = (const char*)xy16 + (size_t)gi[mi] * 256; \
        dst[mi] = *(const f16x8*)(row + ((kf) << 6) + (g4 << 4)); \
    } } while (0)

#define COMP1(ab, kf) do { \
    _Pragma("unroll") for (int nf = 0; nf < 4; ++nf) { \
        const int addr = ((((16 * nf + c) << 8) + ((kf) << 6) + (g4 << 4))) ^ (c << 4); \
        const f16x8 wb = *(const f16x8*)&wsh[addr]; \
        _Pragma("unroll") for (int mi = 0; mi < 2; ++mi) \
            acc[mi][nf] = MFMA16(ab[mi], wb, acc[mi][nf]); \
    } } while (0)

#define STAGE_W1(tp) do { \
    const char* src = (const char*)w1t + (size_t)(tp) * 16384 + wv * 4096 + ln * 16; \
    _Pragma("unroll") for (int i = 0; i < 4; ++i) \
        gload_lds16(src + i * 1024, &wsh[wv * 4096 + i * 1024]); \
    } while (0)

    // prologue
    LOAD_IDX1(gi, 0);
    LOAD_IDX1(gin, 1);
    STAGE_W1(0);
    GPRE1(aA, 0);
    GPRE1(aB, 1);
    __syncthreads();

    for (int tap = 0; ; ++tap) {
        COMP1(aA, 0);
        GPRE1(aA, 2);
        COMP1(aB, 1);
        GPRE1(aB, 3);
        COMP1(aA, 2);
        const bool more = (tap + 1 < TAPS);
        if (more) {
#pragma unroll
            for (int mi = 0; mi < 2; ++mi) gi[mi] = gin[mi];
            const int tp2 = (tap + 2 < TAPS) ? tap + 2 : TAPS - 1;
            LOAD_IDX1(gin, tp2);
            GPRE1(aA, 0);                 // next tap kf0 (W-independent)
        }
        COMP1(aB, 3);
        if (!more) break;
        __syncthreads();                  // all reads of W(tap) done
        STAGE_W1(tap + 1);                // refill single buffer
        GPRE1(aB, 1);                     // next tap kf1
        __syncthreads();                  // W(tap+1) visible
    }

    // epilogue: relu, fp16-quantize, store h16 rows
#pragma unroll
    for (int mi = 0; mi < 2; ++mi)
#pragma unroll
        for (int nf = 0; nf < 4; ++nf)
#pragma unroll
            for (int r = 0; r < 4; ++r) {
                const int pt = base + mi * 16 + (g4 << 2) + r;
                h16[(size_t)pt * 64 + 16 * nf + c] =
                    (_Float16)fmaxf(acc[mi][nf][r], 0.f);
            }
#undef LOAD_IDX1
#undef GPRE1
#undef COMP1
#undef STAGE_W1
}

// =====================================================================
// conv2: K=64, A gathered fp16 from h16 (128 B/row), mi=2
// Schedule = r6 VERBATIM; only change: waves/EU 4 -> 5.
// =====================================================================
__global__ __launch_bounds__(256, 5) void conv2_kernel(
    const _Float16* __restrict__ h16,
    const _Float16* __restrict__ w2t,
    const float* __restrict__ b2, const int* __restrict__ nbr,
    float* __restrict__ out)
{
    __shared__ char wsh[8192];   // W[64 col][64 k] fp16, XOR((c&7)<<4)-swizzled

    const int tid = threadIdx.x;
    const int wv = tid >> 6, ln = tid & 63;
    const int g4 = ln >> 4, c = ln & 15;
    const int base = blockIdx.x * 128 + wv * 32;

    f32x4 acc[2][4];
    {
        float bv[4];
#pragma unroll
        for (int nf = 0; nf < 4; ++nf) bv[nf] = b2[16 * nf + c];
#pragma unroll
        for (int mi = 0; mi < 2; ++mi)
#pragma unroll
            for (int nf = 0; nf < 4; ++nf)
                acc[mi][nf] = (f32x4){bv[nf], bv[nf], bv[nf], bv[nf]};
    }

    int gi[2], gin[2];
    f16x8 aA[2], aB[2];

#define LOAD_IDX2(dst, tp) do { \
    _Pragma("unroll") for (int mi = 0; mi < 2; ++mi) \
        dst[mi] = nbr[(size_t)(tp) * NPTS + base + mi * 16 + c]; \
    } while (0)

#define GPRE2(dst, kf) do { \
    _Pragma("unroll") for (int mi = 0; mi < 2; ++mi) { \
        const char* row = (const char*)h16 + (size_t)gi[mi] * 128; \
        dst[mi] = *(const f16x8*)(row + ((kf) << 6) + (g4 << 4)); \
    } } while (0)

#define COMP2(ab, kf) do { \
    _Pragma("unroll") for (int nf = 0; nf < 4; ++nf) { \
        const int addr = ((((16 * nf + c) << 7) + ((kf) << 6) + (g4 << 4))) ^ ((c & 7) << 4); \
        const f16x8 wb = *(const f16x8*)&wsh[addr]; \
        _Pragma("unroll") for (int mi = 0; mi < 2; ++mi) \
            acc[mi][nf] = MFMA16(ab[mi], wb, acc[mi][nf]); \
    } } while (0)

#define STAGE_W2(tp) do { \
    const char* src = (const char*)w2t + (size_t)(tp) * 8192 + wv * 2048 + ln * 16; \
    _Pragma("unroll") for (int i = 0; i < 2; ++i) \
        gload_lds16(src + i * 1024, &wsh[wv * 2048 + i * 1024]); \
    } while (0)

    LOAD_IDX2(gi, 0);
    LOAD_IDX2(gin, 1);
    STAGE_W2(0);
    GPRE2(aA, 0);
    GPRE2(aB, 1);
    __syncthreads();

    for (int tap = 0; ; ++tap) {
        COMP2(aA, 0);
        const bool more = (tap + 1 < TAPS);
        if (more) {
#pragma unroll
            for (int mi = 0; mi < 2; ++mi) gi[mi] = gin[mi];
            const int tp2 = (tap + 2 < TAPS) ? tap + 2 : TAPS - 1;
            LOAD_IDX2(gin, tp2);
            GPRE2(aA, 0);                 // next tap kf0
        }
        COMP2(aB, 1);
        if (!more) break;
        __syncthreads();
        STAGE_W2(tap + 1);
        GPRE2(aB, 1);                     // next tap kf1
        __syncthreads();
    }

#pragma unroll
    for (int mi = 0; mi < 2; ++mi)
#pragma unroll
        for (int nf = 0; nf < 4; ++nf)
#pragma unroll
            for (int r = 0; r < 4; ++r) {
                const int pt = base + mi * 16 + (g4 << 2) + r;
                out[(size_t)pt * 64 + 16 * nf + c] =
                    fminf(fmaxf(acc[mi][nf][r], -2.f), 2.f);
            }
#undef LOAD_IDX2
#undef GPRE2
#undef COMP2
#undef STAGE_W2
}

extern "C" void kernel_launch(void* const* d_in, const int* in_sizes, int n_in,
                              void* d_out, int out_size, void* d_ws, size_t ws_size,
                              hipStream_t stream) {
    const float* x  = (const float*)d_in[0];
    const float* y  = (const float*)d_in[1];
    const float* w1 = (const float*)d_in[2];
    const float* b1 = (const float*)d_in[3];
    const float* w2 = (const float*)d_in[4];
    const float* b2 = (const float*)d_in[5];
    const int* nbr  = (const int*)d_in[6];
    float* out = (float*)d_out;

    char* ws = (char*)d_ws;
    _Float16* h16  = (_Float16*)ws;
    _Float16* w1t  = (_Float16*)(ws + W1T_OFF);
    _Float16* w2t  = (_Float16*)(ws + W2T_OFF);
    _Float16* xy16 = (_Float16*)(ws + XY16_OFF);

    const int prep_threads = TAPS * 64 * 128 + TAPS * 64 * 64 + 64;
    prep_weights<<<(prep_threads + 255) / 256, 256, 0, stream>>>(w1, w2, w1t, w2t, h16);

    const int pxy_threads = (NPTS + 1) * 16;
    prep_xy16<<<(pxy_threads + 255) / 256, 256, 0, stream>>>(x, y, xy16);

    conv1_kernel<<<NPTS / 128, 256, 0, stream>>>(xy16, w1t, b1, nbr, h16);
    conv2_kernel<<<NPTS / 128, 256, 0, stream>>>(h16, w2t, b2, nbr, out);
}

// Round 12
// 419.129 us; speedup vs baseline: 1.1166x; 1.1166x over previous
//
#include <hip/hip_runtime.h>
#include <stdint.h>

// SubResidualGeoLossl on MI355X — fp16 single-term MFMA (r6 config, FINAL).
//   h   = relu( sum_k gather(concat(x,y), nbr[k]) @ w1[k] + b1 )   K=128
//   out = clip( sum_k gather(h,           nbr[k]) @ w2[k] + b2 , -2, 2)  K=64
//
// Ledger of failed variants (all single-variable tested):
//   r7  burst A-prefetch: +70MB refetch, -23%     r8 w=8: spill (+1.2GB), -2.3x
//   r9  w=6: spill (+0.7GB), -2x                  r10 mi=1/8-wave: clean, -9%
//   r11 w=5: allocator squeeze (VGPR 48), -18%
// Conclusion: conv kernels are per-CU L1-miss-queue-bound on the random
// gather at L3 latency (~625MB real lines @ ~2.4TB/s); occupancy/ILP invariant.
// w=4 + mi=2 + 1-kf-interleaved prefetch + single-buffer W (2 barriers/tap)
// is the optimum of this family. fp16 is the thinnest dtype passing 0.04.

#define NPTS 400000
#define TAPS 27

typedef __attribute__((ext_vector_type(8))) _Float16 f16x8;
typedef __attribute__((ext_vector_type(4))) float f32x4;

#define MFMA16(a, b, c) __builtin_amdgcn_mfma_f32_16x16x32_f16(a, b, c, 0, 0, 0)

// ---- scratch layout (bytes) ----
// h16:  [NPTS+1][64] fp16 (128 B/row, row NPTS zero)              51.2 MB
// w1t:  [27][64 col][128 k] fp16, pre-swizzled q^=((q>>8)&15)<<4   432 KB
// w2t:  [27][64 col][64 k]  fp16, pre-swizzled q^=((q>>7)&7)<<4    216 KB
// xy16: [NPTS+1][128] fp16 (256 B/row, row NPTS zero)            102.4 MB
#define H16_BYTES ((size_t)(NPTS + 1) * 128)
#define W1T_SZ    ((size_t)TAPS * 64 * 128 * 2)
#define W2T_SZ    ((size_t)TAPS * 64 * 64 * 2)
#define W1T_OFF   (H16_BYTES)
#define W2T_OFF   (W1T_OFF + W1T_SZ)
#define XY16_OFF  (W2T_OFF + W2T_SZ)

__device__ inline void gload_lds16(const void* g, void* l) {
    __builtin_amdgcn_global_load_lds((const __attribute__((address_space(1))) void*)g,
                                     (__attribute__((address_space(3))) void*)l, 16, 0, 0);
}

// ---- prep: transpose + fp16-quantize + PRE-SWIZZLE weights; zero h16 sentinel ----
__global__ __launch_bounds__(256) void prep_weights(
    const float* __restrict__ w1, const float* __restrict__ w2,
    _Float16* __restrict__ w1t, _Float16* __restrict__ w2t,
    _Float16* __restrict__ h16)
{
    const int gid = blockIdx.x * 256 + threadIdx.x;
    const int n1 = TAPS * 64 * 128;   // 221184
    const int n2 = TAPS * 64 * 64;    // 110592
    if (gid < n1) {
        const int tap = gid >> 13;
        const int q  = (gid & 8191) << 1;            // byte within 16KB tap block
        const int sb = q ^ (((q >> 8) & 15) << 4);   // inverse swizzle (involution)
        const int col = sb >> 8, k = (sb & 255) >> 1;
        w1t[gid] = (_Float16)w1[((size_t)tap * 128 + k) * 64 + col];
    } else if (gid < n1 + n2) {
        const int g = gid - n1;
        const int tap = g >> 12;
        const int q  = (g & 4095) << 1;              // byte within 8KB tap block
        const int sb = q ^ (((q >> 7) & 7) << 4);
        const int col = sb >> 7, k = (sb & 127) >> 1;
        w2t[g] = (_Float16)w2[((size_t)tap * 64 + k) * 64 + col];
    } else if (gid < n1 + n2 + 64) {
        h16[(size_t)NPTS * 64 + (gid - n1 - n2)] = (_Float16)0.f;  // sentinel row
    }
}

// ---- prep: concat(x,y) -> fp16 rows [NPTS+1][128] (sentinel row zero) ----
__global__ __launch_bounds__(256) void prep_xy16(
    const float* __restrict__ x, const float* __restrict__ y,
    _Float16* __restrict__ xy16)
{
    const int gid = blockIdx.x * 256 + threadIdx.x;
    if (gid >= (NPTS + 1) * 16) return;
    const int p = gid >> 4, seg = gid & 15;   // seg: 8-channel group of concat(x,y)
    f32x4 v0 = {0.f, 0.f, 0.f, 0.f}, v1 = {0.f, 0.f, 0.f, 0.f};
    if (p < NPTS) {
        const float* s = (seg < 8) ? (x + (size_t)p * 64 + seg * 8)
                                   : (y + (size_t)p * 64 + (seg - 8) * 8);
        v0 = *(const f32x4*)s; v1 = *(const f32x4*)(s + 4);
    }
    _Float16 h[8];
#pragma unroll
    for (int j = 0; j < 4; ++j) { h[j] = (_Float16)v0[j]; h[4 + j] = (_Float16)v1[j]; }
    *(f16x8*)&xy16[(size_t)p * 128 + seg * 8] = *(f16x8*)h;
}

// =====================================================================
// conv1: K=128, A gathered fp16 from xy16 (256 B/row), mi=2  (r6 verbatim)
// =====================================================================
__global__ __launch_bounds__(256, 4) void conv1_kernel(
    const _Float16* __restrict__ xy16,
    const _Float16* __restrict__ w1t,
    const float* __restrict__ b1, const int* __restrict__ nbr,
    _Float16* __restrict__ h16)
{
    __shared__ char wsh[16384];   // W[64 col][128 k] fp16, XOR(c<<4)-swizzled

    const int tid = threadIdx.x;
    const int wv = tid >> 6, ln = tid & 63;
    const int g4 = ln >> 4, c = ln & 15;
    const int base = blockIdx.x * 128 + wv * 32;

    f32x4 acc[2][4];
    {
        float bv[4];
#pragma unroll
        for (int nf = 0; nf < 4; ++nf) bv[nf] = b1[16 * nf + c];
#pragma unroll
        for (int mi = 0; mi < 2; ++mi)
#pragma unroll
            for (int nf = 0; nf < 4; ++nf)
                acc[mi][nf] = (f32x4){bv[nf], bv[nf], bv[nf], bv[nf]};
    }

    int gi[2], gin[2];
    f16x8 aA[2], aB[2];

#define LOAD_IDX1(dst, tp) do { \
    _Pragma("unroll") for (int mi = 0; mi < 2; ++mi) \
        dst[mi] = nbr[(size_t)(tp) * NPTS + base + mi * 16 + c]; \
    } while (0)

#define GPRE1(dst, kf) do { \
    _Pragma("unroll") for (int mi = 0; mi < 2; ++mi) { \
        const char* row = (const char*)xy16 + (size_t)gi[mi] * 256; \
        dst[mi] = *(const f16x8*)(row + ((kf) << 6) + (g4 << 4)); \
    } } while (0)

#define COMP1(ab, kf) do { \
    _Pragma("unroll") for (int nf = 0; nf < 4; ++nf) { \
        const int addr = ((((16 * nf + c) << 8) + ((kf) << 6) + (g4 << 4))) ^ (c << 4); \
        const f16x8 wb = *(const f16x8*)&wsh[addr]; \
        _Pragma("unroll") for (int mi = 0; mi < 2; ++mi) \
            acc[mi][nf] = MFMA16(ab[mi], wb, acc[mi][nf]); \
    } } while (0)

#define STAGE_W1(tp) do { \
    const char* src = (const char*)w1t + (size_t)(tp) * 16384 + wv * 4096 + ln * 16; \
    _Pragma("unroll") for (int i = 0; i < 4; ++i) \
        gload_lds16(src + i * 1024, &wsh[wv * 4096 + i * 1024]); \
    } while (0)

    // prologue
    LOAD_IDX1(gi, 0);
    LOAD_IDX1(gin, 1);
    STAGE_W1(0);
    GPRE1(aA, 0);
    GPRE1(aB, 1);
    __syncthreads();

    for (int tap = 0; ; ++tap) {
        COMP1(aA, 0);
        GPRE1(aA, 2);
        COMP1(aB, 1);
        GPRE1(aB, 3);
        COMP1(aA, 2);
        const bool more = (tap + 1 < TAPS);
        if (more) {
#pragma unroll
            for (int mi = 0; mi < 2; ++mi) gi[mi] = gin[mi];
            const int tp2 = (tap + 2 < TAPS) ? tap + 2 : TAPS - 1;
            LOAD_IDX1(gin, tp2);
            GPRE1(aA, 0);                 // next tap kf0 (W-independent)
        }
        COMP1(aB, 3);
        if (!more) break;
        __syncthreads();                  // all reads of W(tap) done
        STAGE_W1(tap + 1);                // refill single buffer
        GPRE1(aB, 1);                     // next tap kf1
        __syncthreads();                  // W(tap+1) visible
    }

    // epilogue: relu, fp16-quantize, store h16 rows
#pragma unroll
    for (int mi = 0; mi < 2; ++mi)
#pragma unroll
        for (int nf = 0; nf < 4; ++nf)
#pragma unroll
            for (int r = 0; r < 4; ++r) {
                const int pt = base + mi * 16 + (g4 << 2) + r;
                h16[(size_t)pt * 64 + 16 * nf + c] =
                    (_Float16)fmaxf(acc[mi][nf][r], 0.f);
            }
#undef LOAD_IDX1
#undef GPRE1
#undef COMP1
#undef STAGE_W1
}

// =====================================================================
// conv2: K=64, A gathered fp16 from h16 (128 B/row), mi=2  (r6 verbatim)
// =====================================================================
__global__ __launch_bounds__(256, 4) void conv2_kernel(
    const _Float16* __restrict__ h16,
    const _Float16* __restrict__ w2t,
    const float* __restrict__ b2, const int* __restrict__ nbr,
    float* __restrict__ out)
{
    __shared__ char wsh[8192];   // W[64 col][64 k] fp16, XOR((c&7)<<4)-swizzled

    const int tid = threadIdx.x;
    const int wv = tid >> 6, ln = tid & 63;
    const int g4 = ln >> 4, c = ln & 15;
    const int base = blockIdx.x * 128 + wv * 32;

    f32x4 acc[2][4];
    {
        float bv[4];
#pragma unroll
        for (int nf = 0; nf < 4; ++nf) bv[nf] = b2[16 * nf + c];
#pragma unroll
        for (int mi = 0; mi < 2; ++mi)
#pragma unroll
            for (int nf = 0; nf < 4; ++nf)
                acc[mi][nf] = (f32x4){bv[nf], bv[nf], bv[nf], bv[nf]};
    }

    int gi[2], gin[2];
    f16x8 aA[2], aB[2];

#define LOAD_IDX2(dst, tp) do { \
    _Pragma("unroll") for (int mi = 0; mi < 2; ++mi) \
        dst[mi] = nbr[(size_t)(tp) * NPTS + base + mi * 16 + c]; \
    } while (0)

#define GPRE2(dst, kf) do { \
    _Pragma("unroll") for (int mi = 0; mi < 2; ++mi) { \
        const char* row = (const char*)h16 + (size_t)gi[mi] * 128; \
        dst[mi] = *(const f16x8*)(row + ((kf) << 6) + (g4 << 4)); \
    } } while (0)

#define COMP2(ab, kf) do { \
    _Pragma("unroll") for (int nf = 0; nf < 4; ++nf) { \
        const int addr = ((((16 * nf + c) << 7) + ((kf) << 6) + (g4 << 4))) ^ ((c & 7) << 4); \
        const f16x8 wb = *(const f16x8*)&wsh[addr]; \
        _Pragma("unroll") for (int mi = 0; mi < 2; ++mi) \
            acc[mi][nf] = MFMA16(ab[mi], wb, acc[mi][nf]); \
    } } while (0)

#define STAGE_W2(tp) do { \
    const char* src = (const char*)w2t + (size_t)(tp) * 8192 + wv * 2048 + ln * 16; \
    _Pragma("unroll") for (int i = 0; i < 2; ++i) \
        gload_lds16(src + i * 1024, &wsh[wv * 2048 + i * 1024]); \
    } while (0)

    LOAD_IDX2(gi, 0);
    LOAD_IDX2(gin, 1);
    STAGE_W2(0);
    GPRE2(aA, 0);
    GPRE2(aB, 1);
    __syncthreads();

    for (int tap = 0; ; ++tap) {
        COMP2(aA, 0);
        const bool more = (tap + 1 < TAPS);
        if (more) {
#pragma unroll
            for (int mi = 0; mi < 2; ++mi) gi[mi] = gin[mi];
            const int tp2 = (tap + 2 < TAPS) ? tap + 2 : TAPS - 1;
            LOAD_IDX2(gin, tp2);
            GPRE2(aA, 0);                 // next tap kf0
        }
        COMP2(aB, 1);
        if (!more) break;
        __syncthreads();
        STAGE_W2(tap + 1);
        GPRE2(aB, 1);                     // next tap kf1
        __syncthreads();
    }

#pragma unroll
    for (int mi = 0; mi < 2; ++mi)
#pragma unroll
        for (int nf = 0; nf < 4; ++nf)
#pragma unroll
            for (int r = 0; r < 4; ++r) {
                const int pt = base + mi * 16 + (g4 << 2) + r;
                out[(size_t)pt * 64 + 16 * nf + c] =
                    fminf(fmaxf(acc[mi][nf][r], -2.f), 2.f);
            }
#undef LOAD_IDX2
#undef GPRE2
#undef COMP2
#undef STAGE_W2
}

extern "C" void kernel_launch(void* const* d_in, const int* in_sizes, int n_in,
                              void* d_out, int out_size, void* d_ws, size_t ws_size,
                              hipStream_t stream) {
    const float* x  = (const float*)d_in[0];
    const float* y  = (const float*)d_in[1];
    const float* w1 = (const float*)d_in[2];
    const float* b1 = (const float*)d_in[3];
    const float* w2 = (const float*)d_in[4];
    const float* b2 = (const float*)d_in[5];
    const int* nbr  = (const int*)d_in[6];
    float* out = (float*)d_out;

    char* ws = (char*)d_ws;
    _Float16* h16  = (_Float16*)ws;
    _Float16* w1t  = (_Float16*)(ws + W1T_OFF);
    _Float16* w2t  = (_Float16*)(ws + W2T_OFF);
    _Float16* xy16 = (_Float16*)(ws + XY16_OFF);

    const int prep_threads = TAPS * 64 * 128 + TAPS * 64 * 64 + 64;
    prep_weights<<<(prep_threads + 255) / 256, 256, 0, stream>>>(w1, w2, w1t, w2t, h16);

    const int pxy_threads = (NPTS + 1) * 16;
    prep_xy16<<<(pxy_threads + 255) / 256, 256, 0, stream>>>(x, y, xy16);

    conv1_kernel<<<NPTS / 128, 256, 0, stream>>>(xy16, w1t, b1, nbr, h16);
    conv2_kernel<<<NPTS / 128, 256, 0, stream>>>(h16, w2t, b2, nbr, out);
}